// Round 3
// baseline (153.337 us; speedup 1.0000x reference)
//
#include <hip/hip_runtime.h>

// NonlocalWeightedAverage v7: register-trim for true 2-block residency.
// v6 post-mortem: occupancy stuck at 21.7% (1 block/CU, halves run serially;
// 1.44us/step == v4's 1.48). LDS exonerated by v5 (46% occ at same 58,880 B).
// Blocker = per-wave regs (100 arch + ~28 acc) just over the 128 budget for
// 4 waves/SIMD. waves_per_eu(4) is a trap (v5: 64/64 split -> spills).
// v7 trims at source, FP-order-preserving:
//   1) per-kt B loading: B2[2][3] (24 VGPR) live instead of Bf[2][2][3] (48);
//      per-acc (dx outer, ks inner) accumulation order unchanged -> bitwise id.
//   2) cross-step prefetch carried packed (uint4, 4 VGPR) instead of L[8] (8).

#define NPIX 4096
#define ROWCH 528              // 8 kchunks * 66 xslots (xslot 0,65 zero pad)
#define ROWB  (ROWCH * 16)     // 8448 B
#define SCALE 10.0f
#define XCH   2048             // x floats per channel per block (32 rows * 64)

typedef __attribute__((ext_vector_type(8))) short bf16x8;
typedef __attribute__((ext_vector_type(4))) float f32x4;

#define MF(a, b, c) __builtin_amdgcn_mfma_f32_16x16x32_bf16(a, b, c, 0, 0, 0)

__device__ __forceinline__ uint4 pack8(const float* v) {
    unsigned h[8];
#pragma unroll
    for (int j = 0; j < 8; ++j) {
        unsigned u = __float_as_uint(v[j]);
        u = u + 0x7fffu + ((u >> 16) & 1u);   // RNE to bf16
        h[j] = u >> 16;
    }
    return (uint4){h[0] | (h[1] << 16), h[2] | (h[3] << 16),
                   h[4] | (h[5] << 16), h[6] | (h[7] << 16)};
}

__device__ __forceinline__ void load_row(const float* fr, int kc, int x, float* L) {
#pragma unroll
    for (int j = 0; j < 8; ++j) L[j] = fr[(size_t)(kc * 8 + j) * NPIX + x];
}

// 6 MFMAs into acc[T][KT]: dx outer, ks inner == v6's per-element order.
#define MG(T, DBASE, KT) do {                                                 \
    _Pragma("unroll")                                                         \
    for (int dx = 0; dx < 3; ++dx)                                            \
        _Pragma("unroll")                                                     \
        for (int ks = 0; ks < 2; ++ks)                                        \
            acc[T][KT] = MF(AF[((DBASE) + dx) * 2 + ks], B2[ks][dx], acc[T][KT]); \
} while (0)

// myv is LOCAL key row (0..31) within this block's half
#define RETIRE(S, myv) do {                                                   \
    _Pragma("unroll")                                                         \
    for (int kt = 0; kt < 2; ++kt) {                                          \
        const int kx = kh * 32 + kt * 16 + nl;                                \
        const float xv0 = xls[(myv) * 64 + kx];                               \
        const float xv1 = xls[XCH + (myv) * 64 + kx];                         \
        const float xv2 = xls[2 * XCH + (myv) * 64 + kx];                     \
        _Pragma("unroll")                                                     \
        for (int rg = 0; rg < 4; ++rg) {                                      \
            const float e = __expf(fmaf(acc[S][kt][rg], SCALE, negM[rg]));    \
            l_[rg] += e;                                                      \
            A0[rg] = fmaf(e, xv0, A0[rg]);                                    \
            A1[rg] = fmaf(e, xv1, A1[rg]);                                    \
            A2[rg] = fmaf(e, xv2, A2[rg]);                                    \
        }                                                                     \
        acc[S][kt] = (f32x4){0.f, 0.f, 0.f, 0.f};                             \
    }                                                                         \
} while (0)

// Step t processes feature row g(t) = K0 - 1 + t.  Streamed rows: t = 0..33.
// Per step: write packed row g(t+2) into slot SR (t<=31); prefetch+pack row
// g(t+3) (t<=30); MFMA groups dy=2/1/0 guarded by validity; retire my=g-1.
#define STEP(RM, SN, SR, tt) do {                                             \
    const int t_ = (tt);                                                      \
    if (t_ <= 31) *(uint4*)(ring + (SR) * ROWB + wu16) = P;                   \
    if (t_ <= 30) {                                                           \
        const int g3 = K0 + 2 + t_;                                           \
        if (g3 < 64) { load_row(featb + g3 * 64, kc, x, L); P = pack8(L); }   \
        else P = (uint4){0u, 0u, 0u, 0u};                                     \
    }                                                                         \
    if (t_ <= 33) {                                                           \
        const char* base = ring + (RM) * ROWB + bu;                           \
        _Pragma("unroll")                                                     \
        for (int kt = 0; kt < 2; ++kt) {                                      \
            bf16x8 B2[2][3];                                                  \
            _Pragma("unroll")                                                 \
            for (int ks = 0; ks < 2; ++ks) {                                  \
                const char* p = base + (ks * 264 + kt * 16) * 16;             \
                B2[ks][0] = *(const bf16x8*)(p);                              \
                B2[ks][1] = *(const bf16x8*)(p + 16);                         \
                B2[ks][2] = *(const bf16x8*)(p + 32);                         \
            }                                                                 \
            if (t_ >= 2)              MG(SR, 6, kt);   /* my=g-1, dy=2 */     \
            if (t_ >= 1 && t_ <= 32)  MG(RM, 3, kt);   /* my=g,   dy=1 */     \
            if (t_ <= 31)             MG(SN, 0, kt);   /* my=g+1, dy=0 */     \
        }                                                                     \
    }                                                                         \
    if (t_ >= 2 && t_ <= 33) RETIRE(SR, t_ - 2);                              \
    if (t_ <= 33) __syncthreads();                                            \
} while (0)

__global__ __launch_bounds__(512)
__attribute__((amdgpu_waves_per_eu(2)))
void nlwa_fused(const float* __restrict__ x_lab,
                const float* __restrict__ feature,
                float4* __restrict__ ws)
{
    __shared__ __align__(16) char ring[3 * ROWB];   // 25344 B
    __shared__ float xls[3 * XCH];                  // 24576 B
    __shared__ float part[3][8][64];                // 6144 B
    __shared__ float ssq[3][64];                    // 768 B
    __shared__ float4 scrF[64][2];                  // 2048 B
                                                    // total 58880 B -> 2 blk/CU

    const int tid = threadIdx.x;
    const int b = blockIdx.x >> 7;
    const int r7 = blockIdx.x & 127;
    const int ny = r7 >> 1, half = r7 & 1;
    const int K0 = half * 32;                       // first key row of this half
    const int w = tid >> 6, lane = tid & 63;
    const int quad = lane >> 4, nl = lane & 15;
    const int qw = w & 3, kh = w >> 2;              // q quarter, key half
    const int kc = w, x = lane;                     // staging unit (kchunk, col)
    const int wu16 = (kc * 66 + x + 1) * 16;        // this thread's ds_write slot
    const int bu = (quad * 66 + kh * 32 + nl) * 16; // B fragment lane base

    const float* featb = feature + (size_t)b * 64 * NPIX;
    const float* xb = x_lab + (size_t)b * 3 * NPIX;

    // ---- stage x_lab[b] rows K0..K0+31 (24 KB) into LDS ----
    {
        const int base = K0 * 64;
        float4* d4 = (float4*)xls;
        for (int i = tid; i < 3 * XCH / 4; i += 512) {
            const int ch = i >> 9, off = i & 511;   // 512 float4 per channel
            d4[i] = *(const float4*)(xb + (size_t)ch * NPIX + base + off * 4);
        }
    }
    // ---- zero the pad units of all 3 ring slots ----
    if (tid < 48) {
        const int sl = tid / 16, pu = tid % 16;
        const int u = (pu >> 1) * 66 + (pu & 1) * 65;
        *(uint4*)(ring + sl * ROWB + u * 16) = (uint4){0u, 0u, 0u, 0u};
    }

    // ---- convert the 3 query rows into ring slots; ssq partials ----
    float L[8];
#pragma unroll
    for (int dyi = 0; dyi < 3; ++dyi) {
        const int qr = ny + dyi - 1;
        float ss = 0.f;
        if (qr >= 0 && qr < 64) {
            load_row(featb + qr * 64, kc, x, L);
#pragma unroll
            for (int j = 0; j < 8; ++j) ss = fmaf(L[j], L[j], ss);
            *(uint4*)(ring + dyi * ROWB + wu16) = pack8(L);
        } else {
            *(uint4*)(ring + dyi * ROWB + wu16) = (uint4){0u, 0u, 0u, 0u};
        }
        part[dyi][kc][x] = ss;
    }
    __syncthreads();

    if (tid < 192) {
        const int dyi = tid >> 6, xx = tid & 63;
        float s = 0.f;
#pragma unroll
        for (int k = 0; k < 8; ++k) s += part[dyi][k][xx];
        ssq[dyi][xx] = s;
    }

    // ---- A fragments: 18 = 9 (dy,dx) x 2 ks, for this wave's 16 queries ----
    bf16x8 AF[18];
#pragma unroll
    for (int dyi = 0; dyi < 3; ++dyi)
#pragma unroll
        for (int dx = 0; dx < 3; ++dx)
#pragma unroll
            for (int ks = 0; ks < 2; ++ks)
                AF[(dyi * 3 + dx) * 2 + ks] = *(const bf16x8*)(ring + dyi * ROWB +
                    ((quad + ks * 4) * 66 + qw * 16 + nl + dx) * 16);
    __syncthreads();   // ssq ready; AF reads drained before ring overwrite

    // ---- fixed softmax offsets (query side only; identical in both halves) ----
    float negM[4];
#pragma unroll
    for (int rg = 0; rg < 4; ++rg) {
        const int q = qw * 16 + quad * 4 + rg;
        float a = 0.f;
#pragma unroll
        for (int dyi = 0; dyi < 3; ++dyi)
#pragma unroll
            for (int dx = -1; dx <= 1; ++dx) {
                const int cx = q + dx;
                a += (cx >= 0 && cx < 64) ? ssq[dyi][cx] : 0.f;
            }
        negM[rg] = -SCALE * a;
    }

    // ---- stage feature rows g(0)=K0-1, g(1)=K0 into slots 0,1; pre-pack g(2) ----
#pragma unroll
    for (int rr = 0; rr < 2; ++rr) {
        const int g = K0 - 1 + rr;
        if (g >= 0) {
            load_row(featb + g * 64, kc, x, L);
            *(uint4*)(ring + rr * ROWB + wu16) = pack8(L);
        } else {
            *(uint4*)(ring + rr * ROWB + wu16) = (uint4){0u, 0u, 0u, 0u};
        }
    }
    load_row(featb + (K0 + 1) * 64, kc, x, L);      // g(2); always in [0,64)
    uint4 P = pack8(L);

    float l_[4], A0[4], A1[4], A2[4];
#pragma unroll
    for (int rg = 0; rg < 4; ++rg) { l_[rg] = 0.f; A0[rg] = 0.f; A1[rg] = 0.f; A2[rg] = 0.f; }
    f32x4 acc[3][2];
#pragma unroll
    for (int i = 0; i < 3; ++i) {
        acc[i][0] = (f32x4){0.f, 0.f, 0.f, 0.f};
        acc[i][1] = (f32x4){0.f, 0.f, 0.f, 0.f};
    }
    __syncthreads();

    for (int rb = 0; rb < 36; rb += 3) {
        STEP(0, 1, 2, rb);
        STEP(1, 2, 0, rb + 1);
        STEP(2, 0, 1, rb + 2);
    }

    // ---- combine: shfl-reduce 16 key cols, LDS-reduce 2 key halves ----
#pragma unroll
    for (int rg = 0; rg < 4; ++rg) {
#pragma unroll
        for (int off = 8; off >= 1; off >>= 1) {
            l_[rg] += __shfl_down(l_[rg], off, 16);
            A0[rg] += __shfl_down(A0[rg], off, 16);
            A1[rg] += __shfl_down(A1[rg], off, 16);
            A2[rg] += __shfl_down(A2[rg], off, 16);
        }
    }
    if (nl == 0) {
#pragma unroll
        for (int rg = 0; rg < 4; ++rg) {
            const int q = qw * 16 + quad * 4 + rg;
            scrF[q][kh] = make_float4(l_[rg], A0[rg], A1[rg], A2[rg]);
        }
    }
    __syncthreads();
    // ---- partial (l, A0, A1, A2) per query -> workspace ----
    if (tid < 64) {
        const float4 t0 = scrF[tid][0], t1 = scrF[tid][1];
        ws[(size_t)blockIdx.x * 64 + tid] =
            make_float4(t0.x + t1.x, t0.y + t1.y, t0.z + t1.z, t0.w + t1.w);
    }
}

// Combine the two key-half partials and normalize. 4*64*64 = 16384 queries.
__global__ __launch_bounds__(256)
void nlwa_combine(const float4* __restrict__ ws, float* __restrict__ out)
{
    const int i = blockIdx.x * 256 + threadIdx.x;
    const int b = i >> 12, ny = (i >> 6) & 63, q = i & 63;
    const float4 p0 = ws[(size_t)(((b * 64 + ny) * 2) + 0) * 64 + q];
    const float4 p1 = ws[(size_t)(((b * 64 + ny) * 2) + 1) * 64 + q];
    const float inv = 1.0f / (p0.x + p1.x);
    float* o = out + (size_t)b * 3 * NPIX + ny * 64 + q;
    o[0]        = (p0.y + p1.y) * inv;
    o[NPIX]     = (p0.z + p1.z) * inv;
    o[2 * NPIX] = (p0.w + p1.w) * inv;
}

extern "C" void kernel_launch(void* const* d_in, const int* in_sizes, int n_in,
                              void* d_out, int out_size, void* d_ws, size_t ws_size,
                              hipStream_t stream) {
    (void)in_sizes; (void)n_in; (void)out_size; (void)ws_size;
    const float* x_lab   = (const float*)d_in[0];
    const float* feature = (const float*)d_in[1];
    float* out = (float*)d_out;
    float4* ws = (float4*)d_ws;                    // 512 blocks * 64 * 16 B = 512 KB
    nlwa_fused<<<dim3(512), dim3(512), 0, stream>>>(x_lab, feature, ws);
    nlwa_combine<<<dim3(64), dim3(256), 0, stream>>>(ws, out);
}

// Round 4
// 136.483 us; speedup vs baseline: 1.1235x; 1.1235x over previous
//
#include <hip/hip_runtime.h>

// NonlocalWeightedAverage v8: 4-wave blocks so 3 blocks fit the 12 wave slots.
// v7 post-mortem: rocprof VGPR_Count is ARCH regs only; gfx950 unified file
// total (arch+AGPR) is what quantizes occupancy. v5 (64+64=128) got 4
// waves/SIMD (46% occ); v6/v7 (~88-100 arch + ~48 agpr > 128) got 3
// waves/SIMD = 12 slots -> an 8-wave block can't double up -> 1 block/CU.
// v8: 256-thread blocks (4 q-waves, full 64 key cols each, kt=0..3,
// acc[3][4]); keys split 4-way by row (16 rows + halo, 18 steps). LDS
// 41,472 B -> 3 blocks/CU at 3 waves/SIMD; 3-way independent barrier
// overlap. Epilogue simplifies: no cross-wave key-half reduce (scrF gone).

#define NPIX 4096
#define ROWB  (528 * 16)       // 8 kchunks * 66 xslots * 16 B = 8448 B
#define SCALE 10.0f
#define XCH   1024             // x floats per channel per block (16 rows * 64)

typedef __attribute__((ext_vector_type(8))) short bf16x8;
typedef __attribute__((ext_vector_type(4))) float f32x4;

#define MF(a, b, c) __builtin_amdgcn_mfma_f32_16x16x32_bf16(a, b, c, 0, 0, 0)

__device__ __forceinline__ uint4 pack8(const float* v) {
    unsigned h[8];
#pragma unroll
    for (int j = 0; j < 8; ++j) {
        unsigned u = __float_as_uint(v[j]);
        u = u + 0x7fffu + ((u >> 16) & 1u);   // RNE to bf16
        h[j] = u >> 16;
    }
    return (uint4){h[0] | (h[1] << 16), h[2] | (h[3] << 16),
                   h[4] | (h[5] << 16), h[6] | (h[7] << 16)};
}

__device__ __forceinline__ void load_row(const float* fr, int kc, int x, float* L) {
#pragma unroll
    for (int j = 0; j < 8; ++j) L[j] = fr[(size_t)(kc * 8 + j) * NPIX + x];
}

// 6 MFMAs into acc[T][KT]: dx outer, ks inner (v4-proven order).
#define MG(T, DBASE, KT) do {                                                 \
    _Pragma("unroll")                                                         \
    for (int dx = 0; dx < 3; ++dx)                                            \
        _Pragma("unroll")                                                     \
        for (int ks = 0; ks < 2; ++ks)                                        \
            acc[T][KT] = MF(AF[((DBASE) + dx) * 2 + ks], B2[ks][dx], acc[T][KT]); \
} while (0)

// myv is LOCAL key row (0..15) within this block's quarter
#define RETIRE(S, myv) do {                                                   \
    _Pragma("unroll")                                                         \
    for (int kt = 0; kt < 4; ++kt) {                                          \
        const int kx = kt * 16 + nl;                                          \
        const float xv0 = xls[(myv) * 64 + kx];                               \
        const float xv1 = xls[XCH + (myv) * 64 + kx];                         \
        const float xv2 = xls[2 * XCH + (myv) * 64 + kx];                     \
        _Pragma("unroll")                                                     \
        for (int rg = 0; rg < 4; ++rg) {                                      \
            const float e = __expf(fmaf(acc[S][kt][rg], SCALE, negM[rg]));    \
            l_[rg] += e;                                                      \
            A0[rg] = fmaf(e, xv0, A0[rg]);                                    \
            A1[rg] = fmaf(e, xv1, A1[rg]);                                    \
            A2[rg] = fmaf(e, xv2, A2[rg]);                                    \
        }                                                                     \
        acc[S][kt] = (f32x4){0.f, 0.f, 0.f, 0.f};                             \
    }                                                                         \
} while (0)

// Step t processes feature row g(t) = R0 - 1 + t, t = 0..17 (16 rows + halo).
// Per step: write packed row g(t+2) into slot SR (t<=15); prefetch+pack row
// g(t+3) (t<=14, zero when g>=64); MFMA groups dy=2/1/0 guarded; retire
// my = g-1 (local t-2) at t in [2,17].
#define STEP(RM, SN, SR, tt) do {                                             \
    const int t_ = (tt);                                                      \
    if (t_ <= 15) {                                                           \
        *(uint4*)(ring + (SR) * ROWB + wu0) = P0;                             \
        *(uint4*)(ring + (SR) * ROWB + wu1) = P1;                             \
    }                                                                         \
    if (t_ <= 14) {                                                           \
        const int g3 = R0 + 2 + t_;                                           \
        if (g3 < 64) {                                                        \
            load_row(featb + g3 * 64, kc0, x, L); P0 = pack8(L);              \
            load_row(featb + g3 * 64, kc1, x, L); P1 = pack8(L);              \
        } else {                                                              \
            P0 = (uint4){0u, 0u, 0u, 0u}; P1 = (uint4){0u, 0u, 0u, 0u};       \
        }                                                                     \
    }                                                                         \
    {                                                                         \
        const char* base = ring + (RM) * ROWB + bu;                           \
        _Pragma("unroll")                                                     \
        for (int kt = 0; kt < 4; ++kt) {                                      \
            bf16x8 B2[2][3];                                                  \
            _Pragma("unroll")                                                 \
            for (int ks = 0; ks < 2; ++ks) {                                  \
                const char* p = base + (ks * 264 + kt * 16) * 16;             \
                B2[ks][0] = *(const bf16x8*)(p);                              \
                B2[ks][1] = *(const bf16x8*)(p + 16);                         \
                B2[ks][2] = *(const bf16x8*)(p + 32);                         \
            }                                                                 \
            if (t_ >= 2)              MG(SR, 6, kt);   /* my=g-1, dy=2 */     \
            if (t_ >= 1 && t_ <= 16)  MG(RM, 3, kt);   /* my=g,   dy=1 */     \
            if (t_ <= 15)             MG(SN, 0, kt);   /* my=g+1, dy=0 */     \
        }                                                                     \
    }                                                                         \
    if (t_ >= 2) RETIRE(SR, t_ - 2);                                          \
    if (t_ < 17) __syncthreads();                                             \
} while (0)

__global__ __launch_bounds__(256)
__attribute__((amdgpu_waves_per_eu(2)))
void nlwa_fused(const float* __restrict__ x_lab,
                const float* __restrict__ feature,
                float4* __restrict__ ws)
{
    __shared__ __align__(16) char ring[3 * ROWB];   // 25344 B
    __shared__ float xls[3 * XCH];                  // 12288 B
    __shared__ float part[3][4][64];                // 3072 B
    __shared__ float ssq[3][64];                    // 768 B
                                                    // total 41472 B -> 3 blk/CU

    const int tid = threadIdx.x;
    const int b = blockIdx.x >> 8;
    const int rem = blockIdx.x & 255;
    const int ny = rem >> 2, kq = rem & 3;
    const int R0 = kq * 16;                         // first key row of quarter
    const int w = tid >> 6, lane = tid & 63;
    const int quad = lane >> 4, nl = lane & 15;
    const int kc0 = 2 * w, kc1 = 2 * w + 1;         // this thread's 2 kchunks
    const int x = lane;
    const int wu0 = (kc0 * 66 + x + 1) * 16;        // ds_write slots
    const int wu1 = (kc1 * 66 + x + 1) * 16;
    const int bu = (quad * 66 + nl) * 16;           // B fragment lane base

    const float* featb = feature + (size_t)b * 64 * NPIX;
    const float* xb = x_lab + (size_t)b * 3 * NPIX;

    // ---- stage x_lab[b] rows R0..R0+15 (12 KB) into LDS ----
    {
        const int base = R0 * 64;
        float4* d4 = (float4*)xls;
        for (int i = tid; i < 3 * XCH / 4; i += 256) {
            const int ch = i >> 8, off = i & 255;   // 256 float4 per channel
            d4[i] = *(const float4*)(xb + (size_t)ch * NPIX + base + off * 4);
        }
    }
    // ---- zero the pad units of all 3 ring slots ----
    if (tid < 48) {
        const int sl = tid / 16, pu = tid % 16;
        const int u = (pu >> 1) * 66 + (pu & 1) * 65;
        *(uint4*)(ring + sl * ROWB + u * 16) = (uint4){0u, 0u, 0u, 0u};
    }

    // ---- convert the 3 query rows into ring slots; ssq partials ----
    float L[8];
#pragma unroll
    for (int dyi = 0; dyi < 3; ++dyi) {
        const int qr = ny + dyi - 1;
        float ss = 0.f;
        if (qr >= 0 && qr < 64) {
            load_row(featb + qr * 64, kc0, x, L);
#pragma unroll
            for (int j = 0; j < 8; ++j) ss = fmaf(L[j], L[j], ss);
            *(uint4*)(ring + dyi * ROWB + wu0) = pack8(L);
            load_row(featb + qr * 64, kc1, x, L);
#pragma unroll
            for (int j = 0; j < 8; ++j) ss = fmaf(L[j], L[j], ss);
            *(uint4*)(ring + dyi * ROWB + wu1) = pack8(L);
        } else {
            *(uint4*)(ring + dyi * ROWB + wu0) = (uint4){0u, 0u, 0u, 0u};
            *(uint4*)(ring + dyi * ROWB + wu1) = (uint4){0u, 0u, 0u, 0u};
        }
        part[dyi][w][x] = ss;
    }
    __syncthreads();

    if (tid < 192) {
        const int dyi = tid >> 6, xx = tid & 63;
        float s = 0.f;
#pragma unroll
        for (int k = 0; k < 4; ++k) s += part[dyi][k][xx];
        ssq[dyi][xx] = s;
    }

    // ---- A fragments: 18 = 9 (dy,dx) x 2 ks, for this wave's 16 queries ----
    bf16x8 AF[18];
#pragma unroll
    for (int dyi = 0; dyi < 3; ++dyi)
#pragma unroll
        for (int dx = 0; dx < 3; ++dx)
#pragma unroll
            for (int ks = 0; ks < 2; ++ks)
                AF[(dyi * 3 + dx) * 2 + ks] = *(const bf16x8*)(ring + dyi * ROWB +
                    ((quad + ks * 4) * 66 + w * 16 + nl + dx) * 16);
    __syncthreads();   // ssq ready; AF reads drained before ring overwrite

    // ---- fixed softmax offsets (query side only; identical across kq) ----
    float negM[4];
#pragma unroll
    for (int rg = 0; rg < 4; ++rg) {
        const int q = w * 16 + quad * 4 + rg;
        float a = 0.f;
#pragma unroll
        for (int dyi = 0; dyi < 3; ++dyi)
#pragma unroll
            for (int dx = -1; dx <= 1; ++dx) {
                const int cx = q + dx;
                a += (cx >= 0 && cx < 64) ? ssq[dyi][cx] : 0.f;
            }
        negM[rg] = -SCALE * a;
    }

    // ---- stage rows g(0)=R0-1, g(1)=R0 into slots 0,1; pre-pack g(2) ----
#pragma unroll
    for (int rr = 0; rr < 2; ++rr) {
        const int g = R0 - 1 + rr;
        if (g >= 0) {
            load_row(featb + g * 64, kc0, x, L);
            *(uint4*)(ring + rr * ROWB + wu0) = pack8(L);
            load_row(featb + g * 64, kc1, x, L);
            *(uint4*)(ring + rr * ROWB + wu1) = pack8(L);
        } else {
            *(uint4*)(ring + rr * ROWB + wu0) = (uint4){0u, 0u, 0u, 0u};
            *(uint4*)(ring + rr * ROWB + wu1) = (uint4){0u, 0u, 0u, 0u};
        }
    }
    uint4 P0, P1;
    load_row(featb + (R0 + 1) * 64, kc0, x, L); P0 = pack8(L);  // g(2) in [1,49]
    load_row(featb + (R0 + 1) * 64, kc1, x, L); P1 = pack8(L);

    float l_[4], A0[4], A1[4], A2[4];
#pragma unroll
    for (int rg = 0; rg < 4; ++rg) { l_[rg] = 0.f; A0[rg] = 0.f; A1[rg] = 0.f; A2[rg] = 0.f; }
    f32x4 acc[3][4];
#pragma unroll
    for (int i = 0; i < 3; ++i)
#pragma unroll
        for (int kt = 0; kt < 4; ++kt)
            acc[i][kt] = (f32x4){0.f, 0.f, 0.f, 0.f};
    __syncthreads();

    for (int rb = 0; rb < 18; rb += 3) {
        STEP(0, 1, 2, rb);
        STEP(1, 2, 0, rb + 1);
        STEP(2, 0, 1, rb + 2);
    }

    // ---- combine: shfl-reduce the 16 key cols within each quad group ----
#pragma unroll
    for (int rg = 0; rg < 4; ++rg) {
#pragma unroll
        for (int off = 8; off >= 1; off >>= 1) {
            l_[rg] += __shfl_down(l_[rg], off, 16);
            A0[rg] += __shfl_down(A0[rg], off, 16);
            A1[rg] += __shfl_down(A1[rg], off, 16);
            A2[rg] += __shfl_down(A2[rg], off, 16);
        }
    }
    if (nl == 0) {
#pragma unroll
        for (int rg = 0; rg < 4; ++rg) {
            const int q = w * 16 + quad * 4 + rg;
            ws[(size_t)blockIdx.x * 64 + q] =
                make_float4(l_[rg], A0[rg], A1[rg], A2[rg]);
        }
    }
}

// Combine the four key-quarter partials and normalize. 4*64*64 = 16384 queries.
__global__ __launch_bounds__(256)
void nlwa_combine(const float4* __restrict__ ws, float* __restrict__ out)
{
    const int i = blockIdx.x * 256 + threadIdx.x;
    const int b = i >> 12, ny = (i >> 6) & 63, q = i & 63;
    const size_t base = ((size_t)(b * 64 + ny) * 4) * 64 + q;
    float4 s = make_float4(0.f, 0.f, 0.f, 0.f);
#pragma unroll
    for (int kq = 0; kq < 4; ++kq) {
        const float4 p = ws[base + (size_t)kq * 64];
        s.x += p.x; s.y += p.y; s.z += p.z; s.w += p.w;
    }
    const float inv = 1.0f / s.x;
    float* o = out + (size_t)b * 3 * NPIX + ny * 64 + q;
    o[0]        = s.y * inv;
    o[NPIX]     = s.z * inv;
    o[2 * NPIX] = s.w * inv;
}

extern "C" void kernel_launch(void* const* d_in, const int* in_sizes, int n_in,
                              void* d_out, int out_size, void* d_ws, size_t ws_size,
                              hipStream_t stream) {
    (void)in_sizes; (void)n_in; (void)out_size; (void)ws_size;
    const float* x_lab   = (const float*)d_in[0];
    const float* feature = (const float*)d_in[1];
    float* out = (float*)d_out;
    float4* ws = (float4*)d_ws;                    // 1024 blocks * 64 * 16 B = 1 MB
    nlwa_fused<<<dim3(1024), dim3(256), 0, stream>>>(x_lab, feature, ws);
    nlwa_combine<<<dim3(64), dim3(256), 0, stream>>>(ws, out);
}